// Round 1
// baseline (425.182 us; speedup 1.0000x reference)
//
#include <hip/hip_runtime.h>

// Multi-resolution dense 3x3x3 conv, CIN=COUT=16, fp32.
// One block = 512 voxels of exactly one level (levels are >=4096 voxels,
// per-level block table below). Weights for the block's level staged in LDS
// (27*16*16 fp32 = 27.6 KB); all weight reads are wave-uniform broadcasts.

#define TPB 256
#define VPT 2
#define VPB (TPB * VPT)  // 512 voxels per block
#define NBLOCKS 4207

__global__ __launch_bounds__(TPB) void conv3d_mr_kernel(
    const float* __restrict__ in, const float* __restrict__ wgt,
    const float* __restrict__ bias, float* __restrict__ out)
{
    // Static grid layout (matches reference RES/OFF).
    constexpr int RES[16]  = {16, 18, 20, 23, 26, 29, 32, 36, 40, 45, 50, 56, 63, 70, 76, 80};
    constexpr int OFF[16]  = {0, 4096, 9928, 17928, 30095, 47671, 72060, 104828,
                              151484, 215484, 306609, 431609, 607225, 857272, 1200272, 1639248};
    // blocks-per-level prefix (ceil(r^3/512)): 8,12,16,24,35,48,64,92,125,178,245,343,489,670,858,1000
    constexpr int BOFF[16] = {0, 8, 20, 36, 60, 95, 143, 207, 299, 424, 602, 847, 1190, 1679, 2349, 3207};

    __shared__ __align__(16) float w_lds[27 * 256];

    const int b = blockIdx.x;
    int r = RES[0], base = OFF[0], bstart = BOFF[0], lvl = 0;
#pragma unroll
    for (int i = 1; i < 16; ++i) {
        if (b >= BOFF[i]) { lvl = i; r = RES[i]; base = OFF[i]; bstart = BOFF[i]; }
    }
    const int t3 = r * r * r;
    const int vstart = (b - bstart) * VPB;

    // Stage this level's weights into LDS (1728 float4 loads across the block).
    {
        const float4* ws = reinterpret_cast<const float4*>(wgt + lvl * 27 * 256);
        float4* wd = reinterpret_cast<float4*>(w_lds);
        for (int i = threadIdx.x; i < 27 * 64; i += TPB) wd[i] = ws[i];
    }
    __syncthreads();

    // Bias into registers (wave-uniform loads, L2-cached).
    float bv[16];
    {
        const float4* bp = reinterpret_cast<const float4*>(bias + lvl * 16);
#pragma unroll
        for (int j = 0; j < 4; ++j) {
            float4 t = bp[j];
            bv[4 * j + 0] = t.x; bv[4 * j + 1] = t.y; bv[4 * j + 2] = t.z; bv[4 * j + 3] = t.w;
        }
    }

    int  vx[VPT], vy[VPT], vz[VPT];
    bool live[VPT];
    float acc[VPT][16];
#pragma unroll
    for (int i = 0; i < VPT; ++i) {
        int v = vstart + (int)threadIdx.x + i * TPB;
        live[i] = (v < t3);
        if (!live[i]) v = 0;
        const int q = v / r;
        vz[i] = v - q * r;
        vx[i] = q / r;
        vy[i] = q - vx[i] * r;
#pragma unroll
        for (int co = 0; co < 16; ++co) acc[i][co] = bv[co];
    }

#pragma unroll 1
    for (int k = 0; k < 27; ++k) {
        const int dx = k / 9 - 1;
        const int dy = (k / 3) % 3 - 1;
        const int dz = k - (k / 3) * 3 - 1;

        float g[VPT][16];
#pragma unroll
        for (int i = 0; i < VPT; ++i) {
            const int nx = vx[i] + dx, ny = vy[i] + dy, nz = vz[i] + dz;
            const bool ok = live[i] && ((unsigned)nx < (unsigned)r) &&
                            ((unsigned)ny < (unsigned)r) && ((unsigned)nz < (unsigned)r);
            float4 a0 = make_float4(0.f, 0.f, 0.f, 0.f);
            float4 a1 = a0, a2 = a0, a3 = a0;
            if (ok) {
                const float4* p = reinterpret_cast<const float4*>(
                    in + (size_t)(base + (nx * r + ny) * r + nz) * 16);
                a0 = p[0]; a1 = p[1]; a2 = p[2]; a3 = p[3];
            }
            g[i][0]  = a0.x; g[i][1]  = a0.y; g[i][2]  = a0.z; g[i][3]  = a0.w;
            g[i][4]  = a1.x; g[i][5]  = a1.y; g[i][6]  = a1.z; g[i][7]  = a1.w;
            g[i][8]  = a2.x; g[i][9]  = a2.y; g[i][10] = a2.z; g[i][11] = a2.w;
            g[i][12] = a3.x; g[i][13] = a3.y; g[i][14] = a3.z; g[i][15] = a3.w;
        }

        const float4* wk = reinterpret_cast<const float4*>(&w_lds[k * 256]);
#pragma unroll
        for (int ci = 0; ci < 16; ++ci) {
            const float4 w0 = wk[ci * 4 + 0];
            const float4 w1 = wk[ci * 4 + 1];
            const float4 w2 = wk[ci * 4 + 2];
            const float4 w3 = wk[ci * 4 + 3];
#pragma unroll
            for (int i = 0; i < VPT; ++i) {
                const float gv = g[i][ci];
                acc[i][0]  = fmaf(gv, w0.x, acc[i][0]);
                acc[i][1]  = fmaf(gv, w0.y, acc[i][1]);
                acc[i][2]  = fmaf(gv, w0.z, acc[i][2]);
                acc[i][3]  = fmaf(gv, w0.w, acc[i][3]);
                acc[i][4]  = fmaf(gv, w1.x, acc[i][4]);
                acc[i][5]  = fmaf(gv, w1.y, acc[i][5]);
                acc[i][6]  = fmaf(gv, w1.z, acc[i][6]);
                acc[i][7]  = fmaf(gv, w1.w, acc[i][7]);
                acc[i][8]  = fmaf(gv, w2.x, acc[i][8]);
                acc[i][9]  = fmaf(gv, w2.y, acc[i][9]);
                acc[i][10] = fmaf(gv, w2.z, acc[i][10]);
                acc[i][11] = fmaf(gv, w2.w, acc[i][11]);
                acc[i][12] = fmaf(gv, w3.x, acc[i][12]);
                acc[i][13] = fmaf(gv, w3.y, acc[i][13]);
                acc[i][14] = fmaf(gv, w3.z, acc[i][14]);
                acc[i][15] = fmaf(gv, w3.w, acc[i][15]);
            }
        }
    }

#pragma unroll
    for (int i = 0; i < VPT; ++i) {
        if (!live[i]) continue;
        const int v = vstart + (int)threadIdx.x + i * TPB;
        float4* po = reinterpret_cast<float4*>(out + (size_t)(base + v) * 16);
        po[0] = make_float4(acc[i][0],  acc[i][1],  acc[i][2],  acc[i][3]);
        po[1] = make_float4(acc[i][4],  acc[i][5],  acc[i][6],  acc[i][7]);
        po[2] = make_float4(acc[i][8],  acc[i][9],  acc[i][10], acc[i][11]);
        po[3] = make_float4(acc[i][12], acc[i][13], acc[i][14], acc[i][15]);
    }
}

extern "C" void kernel_launch(void* const* d_in, const int* in_sizes, int n_in,
                              void* d_out, int out_size, void* d_ws, size_t ws_size,
                              hipStream_t stream) {
    const float* in   = (const float*)d_in[0];
    // d_in[1] = offsets (int32), d_in[2] = resolutions (int32) — static, baked in.
    const float* wgt  = (const float*)d_in[3];
    const float* bias = (const float*)d_in[4];
    float* out = (float*)d_out;

    conv3d_mr_kernel<<<NBLOCKS, TPB, 0, stream>>>(in, wgt, bias, out);
}

// Round 2
// 184.510 us; speedup vs baseline: 2.3044x; 2.3044x over previous
//
#include <hip/hip_runtime.h>

// Multi-resolution dense 3x3x3 conv, CIN=COUT=16.
// bf16 MFMA path: pass1 converts input fp32->bf16 into d_ws, pass2 builds
// per-level weight B-fragments (MFMA lane layout), pass3 does the conv with
// v_mfma_f32_16x16x32_bf16 (K=32 = 2 kernel-offsets x 16 cin; 27 offsets
// padded to 28 with a zero-weight duplicate-center slot).

typedef short bf16x8 __attribute__((ext_vector_type(8)));   // 8 bf16 = 4 VGPRs
typedef float f32x4  __attribute__((ext_vector_type(4)));

__device__ __forceinline__ unsigned f2bf(float f) {
    unsigned u = __float_as_uint(f);
    return (u + 0x7FFFu + ((u >> 16) & 1u)) >> 16;   // RNE
}

// ---------------- pass 1: input fp32 -> bf16 ----------------
__global__ __launch_bounds__(256) void cvt_kernel(const float* __restrict__ in,
                                                  uint4* __restrict__ outp, int n8) {
    int i = blockIdx.x * 256 + threadIdx.x;
    const int stride = gridDim.x * 256;
    const float4* p4 = reinterpret_cast<const float4*>(in);
    for (; i < n8; i += stride) {
        float4 a = p4[2 * i], b = p4[2 * i + 1];
        uint4 o;
        o.x = f2bf(a.x) | (f2bf(a.y) << 16);
        o.y = f2bf(a.z) | (f2bf(a.w) << 16);
        o.z = f2bf(b.x) | (f2bf(b.y) << 16);
        o.w = f2bf(b.z) | (f2bf(b.w) << 16);
        outp[i] = o;
    }
}

// ---------------- pass 2: weight B-fragments ----------------
// wfrag[lvl][c][lane] = 8 bf16: element j -> w[lvl][s][ci][co],
// s = 2c + (lane>>5), ci = ((lane>>4)&1)*8 + j, co = lane&15; s==27 -> 0.
__global__ __launch_bounds__(64) void wfrag_kernel(const float* __restrict__ wgt,
                                                   uint4* __restrict__ wfrag) {
    const int b = blockIdx.x;            // 0..223 = lvl*14 + c
    const int lvl = b / 14, c = b % 14;
    const int l = threadIdx.x;           // 0..63
    const int s = 2 * c + (l >> 5);
    const int cibase = ((l >> 4) & 1) * 8;
    const int co = l & 15;
    unsigned v[8];
#pragma unroll
    for (int j = 0; j < 8; ++j) {
        float f = 0.f;
        if (s < 27) f = wgt[(((lvl * 27 + s) * 16) + (cibase + j)) * 16 + co];
        v[j] = f2bf(f);
    }
    uint4 pk;
    pk.x = v[0] | (v[1] << 16);
    pk.y = v[2] | (v[3] << 16);
    pk.z = v[4] | (v[5] << 16);
    pk.w = v[6] | (v[7] << 16);
    wfrag[(lvl * 14 + c) * 64 + l] = pk;
}

// ---------------- pass 3: MFMA conv ----------------
__global__ __launch_bounds__(256) void conv_mfma_kernel(
    const ushort* __restrict__ inb, const ushort* __restrict__ wfrag,
    const float* __restrict__ bias, float* __restrict__ out)
{
    constexpr int RES[16]  = {16, 18, 20, 23, 26, 29, 32, 36, 40, 45, 50, 56, 63, 70, 76, 80};
    constexpr int OFF[16]  = {0, 4096, 9928, 17928, 30095, 47671, 72060, 104828,
                              151484, 215484, 306609, 431609, 607225, 857272, 1200272, 1639248};
    // blocks per level = ceil(r^3/256); prefix:
    constexpr int BOFF[16] = {0, 16, 39, 71, 119, 188, 284, 412, 595, 845,
                              1201, 1690, 2376, 3353, 4693, 6408};
    // s -> (dx,dy,dz), s = (dx+1)*9+(dy+1)*3+(dz+1); s==27 -> center (zero weight)
    constexpr int DXT[28] = {-1,-1,-1,-1,-1,-1,-1,-1,-1, 0,0,0,0,0,0,0,0,0, 1,1,1,1,1,1,1,1,1, 0};
    constexpr int DYT[28] = {-1,-1,-1, 0,0,0, 1,1,1, -1,-1,-1, 0,0,0, 1,1,1, -1,-1,-1, 0,0,0, 1,1,1, 0};
    constexpr int DZT[28] = {-1,0,1, -1,0,1, -1,0,1, -1,0,1, -1,0,1, -1,0,1, -1,0,1, -1,0,1, -1,0,1, 0};

    const int b = blockIdx.x;
    int lvl = 0;
#pragma unroll
    for (int i = 1; i < 16; ++i) if (b >= BOFF[i]) lvl = i;
    const int r    = RES[lvl];
    const int base = OFF[lvl];
    const int t3   = r * r * r;

    const int lane = threadIdx.x & 63;
    const int wave = threadIdx.x >> 6;
    const int tile0 = (b - BOFF[lvl]) * 256 + wave * 64;
    const int m    = lane & 15;
    const int ksel = lane >> 5;
    const unsigned cihalf = ((lane >> 4) & 1) * 16;  // byte offset within 32B voxel

    unsigned off32[4], mask27[4];
#pragma unroll
    for (int st = 0; st < 4; ++st) {
        int v = tile0 + st * 16 + m;
        const bool live = v < t3;
        const int vc = live ? v : t3 - 1;
        const int q = vc / r;
        const int z = vc - q * r;
        const int x = q / r;
        const int y = q - x * r;
        unsigned z3  = (z > 0 ? 1u : 0u) | 2u | (z < r - 1 ? 4u : 0u);
        unsigned y9  = (y > 0 ? z3 : 0u) | (z3 << 3) | (y < r - 1 ? (z3 << 6) : 0u);
        unsigned x27 = (x > 0 ? y9 : 0u) | (y9 << 9) | (x < r - 1 ? (y9 << 18) : 0u);
        mask27[st] = live ? x27 : 0u;
        off32[st]  = (unsigned)(base + vc) * 32u + cihalf;
    }

    f32x4 acc[4] = {f32x4{0.f,0.f,0.f,0.f}, f32x4{0.f,0.f,0.f,0.f},
                    f32x4{0.f,0.f,0.f,0.f}, f32x4{0.f,0.f,0.f,0.f}};
    const ushort* wbase = wfrag + (size_t)lvl * 14 * 64 * 8;
    const char* inc = (const char*)inb;

#pragma unroll
    for (int c = 0; c < 14; ++c) {
        const int dx = ksel ? DXT[2*c+1] : DXT[2*c];
        const int dy = ksel ? DYT[2*c+1] : DYT[2*c];
        const int dz = ksel ? DZT[2*c+1] : DZT[2*c];
        const int boff = ((dx * r + dy) * r + dz) * 32;
        const unsigned s = 2 * c + ksel;

        const bf16x8 bfr = *reinterpret_cast<const bf16x8*>(wbase + (c * 64 + lane) * 8);

#pragma unroll
        for (int st = 0; st < 4; ++st) {
            const unsigned ok = (mask27[st] >> s) & 1u;
            const unsigned off = off32[st] + (ok ? (unsigned)boff : 0u);
            bf16x8 af = *reinterpret_cast<const bf16x8*>(inc + off);
            if (!ok) af = bf16x8{0,0,0,0,0,0,0,0};
            acc[st] = __builtin_amdgcn_mfma_f32_16x16x32_bf16(af, bfr, acc[st], 0, 0, 0);
        }
    }

    const float bv = bias[lvl * 16 + m];
#pragma unroll
    for (int st = 0; st < 4; ++st) {
#pragma unroll
        for (int j = 0; j < 4; ++j) {
            const int row = (lane >> 4) * 4 + j;
            const int v = tile0 + st * 16 + row;
            if (v < t3) out[(size_t)(base + v) * 16 + m] = acc[st][j] + bv;
        }
    }
}

// ---------------- fp32 fallback (round-0 verified) ----------------
#define TPB 256
#define VPT 2
#define VPB (TPB * VPT)
#define NBLOCKS_F32 4207

__global__ __launch_bounds__(TPB) void conv3d_mr_kernel(
    const float* __restrict__ in, const float* __restrict__ wgt,
    const float* __restrict__ bias, float* __restrict__ out)
{
    constexpr int RES[16]  = {16, 18, 20, 23, 26, 29, 32, 36, 40, 45, 50, 56, 63, 70, 76, 80};
    constexpr int OFF[16]  = {0, 4096, 9928, 17928, 30095, 47671, 72060, 104828,
                              151484, 215484, 306609, 431609, 607225, 857272, 1200272, 1639248};
    constexpr int BOFF[16] = {0, 8, 20, 36, 60, 95, 143, 207, 299, 424, 602, 847, 1190, 1679, 2349, 3207};

    __shared__ __align__(16) float w_lds[27 * 256];

    const int b = blockIdx.x;
    int r = RES[0], base = OFF[0], bstart = BOFF[0], lvl = 0;
#pragma unroll
    for (int i = 1; i < 16; ++i)
        if (b >= BOFF[i]) { lvl = i; r = RES[i]; base = OFF[i]; bstart = BOFF[i]; }
    const int t3 = r * r * r;
    const int vstart = (b - bstart) * VPB;

    {
        const float4* ws = reinterpret_cast<const float4*>(wgt + lvl * 27 * 256);
        float4* wd = reinterpret_cast<float4*>(w_lds);
        for (int i = threadIdx.x; i < 27 * 64; i += TPB) wd[i] = ws[i];
    }
    __syncthreads();

    float bv[16];
    {
        const float4* bp = reinterpret_cast<const float4*>(bias + lvl * 16);
#pragma unroll
        for (int j = 0; j < 4; ++j) {
            float4 t = bp[j];
            bv[4*j+0] = t.x; bv[4*j+1] = t.y; bv[4*j+2] = t.z; bv[4*j+3] = t.w;
        }
    }

    int vx[VPT], vy[VPT], vz[VPT];
    bool live[VPT];
    float acc[VPT][16];
#pragma unroll
    for (int i = 0; i < VPT; ++i) {
        int v = vstart + (int)threadIdx.x + i * TPB;
        live[i] = (v < t3);
        if (!live[i]) v = 0;
        const int q = v / r;
        vz[i] = v - q * r; vx[i] = q / r; vy[i] = q - vx[i] * r;
#pragma unroll
        for (int co = 0; co < 16; ++co) acc[i][co] = bv[co];
    }

#pragma unroll 1
    for (int k = 0; k < 27; ++k) {
        const int dx = k / 9 - 1, dy = (k / 3) % 3 - 1, dz = k - (k / 3) * 3 - 1;
        float g[VPT][16];
#pragma unroll
        for (int i = 0; i < VPT; ++i) {
            const int nx = vx[i] + dx, ny = vy[i] + dy, nz = vz[i] + dz;
            const bool ok = live[i] && ((unsigned)nx < (unsigned)r) &&
                            ((unsigned)ny < (unsigned)r) && ((unsigned)nz < (unsigned)r);
            float4 a0 = make_float4(0.f,0.f,0.f,0.f), a1 = a0, a2 = a0, a3 = a0;
            if (ok) {
                const float4* p = reinterpret_cast<const float4*>(
                    in + (size_t)(base + (nx * r + ny) * r + nz) * 16);
                a0 = p[0]; a1 = p[1]; a2 = p[2]; a3 = p[3];
            }
            g[i][0]=a0.x; g[i][1]=a0.y; g[i][2]=a0.z; g[i][3]=a0.w;
            g[i][4]=a1.x; g[i][5]=a1.y; g[i][6]=a1.z; g[i][7]=a1.w;
            g[i][8]=a2.x; g[i][9]=a2.y; g[i][10]=a2.z; g[i][11]=a2.w;
            g[i][12]=a3.x; g[i][13]=a3.y; g[i][14]=a3.z; g[i][15]=a3.w;
        }
        const float4* wk = reinterpret_cast<const float4*>(&w_lds[k * 256]);
#pragma unroll
        for (int ci = 0; ci < 16; ++ci) {
            const float4 w0 = wk[ci*4+0], w1 = wk[ci*4+1], w2 = wk[ci*4+2], w3 = wk[ci*4+3];
#pragma unroll
            for (int i = 0; i < VPT; ++i) {
                const float gv = g[i][ci];
                acc[i][0]=fmaf(gv,w0.x,acc[i][0]);   acc[i][1]=fmaf(gv,w0.y,acc[i][1]);
                acc[i][2]=fmaf(gv,w0.z,acc[i][2]);   acc[i][3]=fmaf(gv,w0.w,acc[i][3]);
                acc[i][4]=fmaf(gv,w1.x,acc[i][4]);   acc[i][5]=fmaf(gv,w1.y,acc[i][5]);
                acc[i][6]=fmaf(gv,w1.z,acc[i][6]);   acc[i][7]=fmaf(gv,w1.w,acc[i][7]);
                acc[i][8]=fmaf(gv,w2.x,acc[i][8]);   acc[i][9]=fmaf(gv,w2.y,acc[i][9]);
                acc[i][10]=fmaf(gv,w2.z,acc[i][10]); acc[i][11]=fmaf(gv,w2.w,acc[i][11]);
                acc[i][12]=fmaf(gv,w3.x,acc[i][12]); acc[i][13]=fmaf(gv,w3.y,acc[i][13]);
                acc[i][14]=fmaf(gv,w3.z,acc[i][14]); acc[i][15]=fmaf(gv,w3.w,acc[i][15]);
            }
        }
    }

#pragma unroll
    for (int i = 0; i < VPT; ++i) {
        if (!live[i]) continue;
        const int v = vstart + (int)threadIdx.x + i * TPB;
        float4* po = reinterpret_cast<float4*>(out + (size_t)(base + v) * 16);
        po[0] = make_float4(acc[i][0],  acc[i][1],  acc[i][2],  acc[i][3]);
        po[1] = make_float4(acc[i][4],  acc[i][5],  acc[i][6],  acc[i][7]);
        po[2] = make_float4(acc[i][8],  acc[i][9],  acc[i][10], acc[i][11]);
        po[3] = make_float4(acc[i][12], acc[i][13], acc[i][14], acc[i][15]);
    }
}

extern "C" void kernel_launch(void* const* d_in, const int* in_sizes, int n_in,
                              void* d_out, int out_size, void* d_ws, size_t ws_size,
                              hipStream_t stream) {
    const float* in   = (const float*)d_in[0];
    const float* wgt  = (const float*)d_in[3];
    const float* bias = (const float*)d_in[4];
    float* out = (float*)d_out;

    constexpr int    N        = 2151248;
    constexpr size_t BF_BYTES = (size_t)N * 32;            // 68,839,936
    constexpr size_t WF_BYTES = 16 * 14 * 64 * 16;         // 229,376
    if (ws_size < BF_BYTES + WF_BYTES) {
        conv3d_mr_kernel<<<NBLOCKS_F32, TPB, 0, stream>>>(in, wgt, bias, out);
        return;
    }

    ushort* inb   = (ushort*)d_ws;
    uint4*  wfrag = (uint4*)((char*)d_ws + BF_BYTES);

    cvt_kernel<<<2048, 256, 0, stream>>>(in, (uint4*)inb, N * 16 / 8);
    wfrag_kernel<<<16 * 14, 64, 0, stream>>>(wgt, wfrag);
    conv_mfma_kernel<<<8408, 256, 0, stream>>>(inb, (const ushort*)wfrag, bias, out);
}

// Round 3
// 96.576 us; speedup vs baseline: 4.4026x; 1.9105x over previous
//
#include <hip/hip_runtime.h>

// Multi-resolution dense 3x3x3 conv, CIN=COUT=16, bf16 MFMA with 3D LDS tiling.
// Block = 512 thr (8 waves) owns an 8x8x16 voxel tile of one level.
// Stage: fp32 global -> bf16 LDS halo (10x10x18 voxels, zero-padded at level
// borders), stored as two ci-half planes (16B/voxel each) so ds_read_b128
// phases are contiguous. Compute: per wave 8 z-columns x 14 MFMAs
// (v_mfma_f32_16x16x32_bf16, K=32 = 2 kernel offsets x 16 cin; offset 27 is a
// zero-weight pad). No per-MFMA masking: halo zeros handle borders.

typedef short bf16x8 __attribute__((ext_vector_type(8)));   // 8 bf16 = 4 VGPRs
typedef float f32x4  __attribute__((ext_vector_type(4)));

__device__ __forceinline__ unsigned f2bf(float f) {
    unsigned u = __float_as_uint(f);
    return (u + 0x7FFFu + ((u >> 16) & 1u)) >> 16;   // RNE
}

// ---------------- pass 1: weight B-fragments (verified round-1 layout) -------
// wfrag[lvl][c][lane] = 8 bf16: element j -> w[lvl][s][ci][co],
// s = 2c + (lane>>5), ci = ((lane>>4)&1)*8 + j, co = lane&15; s==27 -> 0.
__global__ __launch_bounds__(64) void wfrag_kernel(const float* __restrict__ wgt,
                                                   uint4* __restrict__ wfrag) {
    const int b = blockIdx.x;            // 0..223 = lvl*14 + c
    const int lvl = b / 14, c = b % 14;
    const int l = threadIdx.x;           // 0..63
    const int s = 2 * c + (l >> 5);
    const int cibase = ((l >> 4) & 1) * 8;
    const int co = l & 15;
    unsigned v[8];
#pragma unroll
    for (int j = 0; j < 8; ++j) {
        float f = 0.f;
        if (s < 27) f = wgt[(((lvl * 27 + s) * 16) + (cibase + j)) * 16 + co];
        v[j] = f2bf(f);
    }
    uint4 pk;
    pk.x = v[0] | (v[1] << 16);
    pk.y = v[2] | (v[3] << 16);
    pk.z = v[4] | (v[5] << 16);
    pk.w = v[6] | (v[7] << 16);
    wfrag[(lvl * 14 + c) * 64 + l] = pk;
}

// ---------------- pass 2: tiled MFMA conv ----------------
#define CTPB 512
#define NTILEBLKS 2465
#define PLANE 28800          // 1800 halo voxels * 16B per ci-half plane

__global__ __launch_bounds__(CTPB, 4) void conv_mfma_tile_kernel(
    const float* __restrict__ in, const ushort* __restrict__ wfrag,
    const float* __restrict__ bias, float* __restrict__ out)
{
    constexpr int RES[16]   = {16, 18, 20, 23, 26, 29, 32, 36, 40, 45, 50, 56, 63, 70, 76, 80};
    constexpr int OFF[16]   = {0, 4096, 9928, 17928, 30095, 47671, 72060, 104828,
                               151484, 215484, 306609, 431609, 607225, 857272, 1200272, 1639248};
    // tiles per level = ceil(r/8)^2 * ceil(r/16); prefix:
    constexpr int TBOFF[16] = {0, 4, 22, 40, 58, 90, 122, 154, 229, 304, 412, 608, 804, 1060, 1465, 1965};
    // s -> (dx,dy,dz), s = (dx+1)*9+(dy+1)*3+(dz+1); s==27 -> center (zero weight)
    constexpr int DXT[28] = {-1,-1,-1,-1,-1,-1,-1,-1,-1, 0,0,0,0,0,0,0,0,0, 1,1,1,1,1,1,1,1,1, 0};
    constexpr int DYT[28] = {-1,-1,-1, 0,0,0, 1,1,1, -1,-1,-1, 0,0,0, 1,1,1, -1,-1,-1, 0,0,0, 1,1,1, 0};
    constexpr int DZT[28] = {-1,0,1, -1,0,1, -1,0,1, -1,0,1, -1,0,1, -1,0,1, -1,0,1, -1,0,1, -1,0,1, 0};

    __shared__ __align__(16) char lds[2 * PLANE];   // 57.6 KB

    const int b = blockIdx.x;
    int lvl = 0;
#pragma unroll
    for (int i = 1; i < 16; ++i) if (b >= TBOFF[i]) lvl = i;
    const int r    = RES[lvl];
    const int base = OFF[lvl];

    const int NTZ = (r + 15) >> 4;
    const int NTY = (r + 7) >> 3;
    int tid = b - TBOFF[lvl];
    const int nyz = NTY * NTZ;
    const int txi = tid / nyz;  tid -= txi * nyz;
    const int tyi = tid / NTZ;
    const int tzi = tid - tyi * NTZ;
    const int x0 = txi * 8, y0 = tyi * 8, z0 = tzi * 16;

    const int lane = threadIdx.x & 63;
    const int wave = threadIdx.x >> 6;

    // Preload this level's 14 weight fragments (issued before staging; latency
    // hidden under the staging loop).
    bf16x8 wfr[14];
    {
        const bf16x8* wb = (const bf16x8*)wfrag + (size_t)lvl * 14 * 64 + lane;
#pragma unroll
        for (int c = 0; c < 14; ++c) wfr[c] = wb[c * 64];
    }

    // ---- stage halo: fp32 global -> bf16 LDS (zeros outside level bounds) ----
    for (int j = threadIdx.x; j < 3600; j += CTPB) {
        const int h = j >> 1, half = j & 1;          // halo voxel, ci-half
        const int hx = h / 180;
        const int rem = h - hx * 180;
        const int hy = rem / 18;
        const int hz = rem - hy * 18;
        const int gx = x0 - 1 + hx, gy = y0 - 1 + hy, gz = z0 - 1 + hz;
        uint4 pk = {0u, 0u, 0u, 0u};
        if (((unsigned)gx < (unsigned)r) & ((unsigned)gy < (unsigned)r) &
            ((unsigned)gz < (unsigned)r)) {
            const float4* s = reinterpret_cast<const float4*>(
                in + ((size_t)base + ((size_t)gx * r + gy) * r + gz) * 16 + half * 8);
            const float4 a = s[0], c2 = s[1];
            pk.x = f2bf(a.x)  | (f2bf(a.y)  << 16);
            pk.y = f2bf(a.z)  | (f2bf(a.w)  << 16);
            pk.z = f2bf(c2.x) | (f2bf(c2.y) << 16);
            pk.w = f2bf(c2.z) | (f2bf(c2.w) << 16);
        }
        *reinterpret_cast<uint4*>(lds + half * PLANE + h * 16) = pk;
    }
    __syncthreads();

    // ---- compute: wave = x-column tx, 8 y-columns each, 14 MFMAs/column ----
    const int m      = lane & 15;         // MFMA A row = z within tile
    const int cihalf = (lane >> 4) & 1;   // which ci-half plane
    const int ksel   = lane >> 5;         // which of the 2 packed offsets
    const int tx     = wave;

    // per-lane static LDS byte offset (i-th y-column adds i*288)
    const int pbase = cihalf * PLANE + (((tx + 1) * 180) + 18 + 1 + m) * 16;

    f32x4 acc[8];
#pragma unroll
    for (int i = 0; i < 8; ++i) acc[i] = f32x4{0.f, 0.f, 0.f, 0.f};

#pragma unroll
    for (int c = 0; c < 14; ++c) {
        const int s0 = 2 * c, s1 = 2 * c + 1;
        const int d0 = (DXT[s0] * 180 + DYT[s0] * 18 + DZT[s0]) * 16;
        const int d1 = (DXT[s1] * 180 + DYT[s1] * 18 + DZT[s1]) * 16;
        const int dof = ksel ? d1 : d0;
        const char* ap = lds + (pbase + dof);
#pragma unroll
        for (int i = 0; i < 8; ++i) {
            const bf16x8 a = *reinterpret_cast<const bf16x8*>(ap + i * 288);
            acc[i] = __builtin_amdgcn_mfma_f32_16x16x32_bf16(a, wfr[c], acc[i], 0, 0, 0);
        }
    }

    // ---- store (+bias); C layout: col=lane&15=co, row=(lane>>4)*4+reg ----
    const int co = m;
    const float bv = bias[lvl * 16 + co];
    const int gx = x0 + tx;
    if (gx < r) {
#pragma unroll
        for (int i = 0; i < 8; ++i) {
            const int gy = y0 + i;
            if (gy >= r) continue;
            const size_t vb = (size_t)base + ((size_t)gx * r + gy) * r + z0;
#pragma unroll
            for (int j2 = 0; j2 < 4; ++j2) {
                const int row = (lane >> 4) * 4 + j2;
                if (z0 + row < r) out[(vb + row) * 16 + co] = acc[i][j2] + bv;
            }
        }
    }
}

// ---------------- fp32 fallback (round-0 verified, used only if ws tiny) -----
#define TPB 256
#define VPT 2
#define VPB (TPB * VPT)
#define NBLOCKS_F32 4207

__global__ __launch_bounds__(TPB) void conv3d_mr_kernel(
    const float* __restrict__ in, const float* __restrict__ wgt,
    const float* __restrict__ bias, float* __restrict__ out)
{
    constexpr int RES[16]  = {16, 18, 20, 23, 26, 29, 32, 36, 40, 45, 50, 56, 63, 70, 76, 80};
    constexpr int OFF[16]  = {0, 4096, 9928, 17928, 30095, 47671, 72060, 104828,
                              151484, 215484, 306609, 431609, 607225, 857272, 1200272, 1639248};
    constexpr int BOFF[16] = {0, 8, 20, 36, 60, 95, 143, 207, 299, 424, 602, 847, 1190, 1679, 2349, 3207};

    __shared__ __align__(16) float w_lds[27 * 256];

    const int b = blockIdx.x;
    int r = RES[0], base = OFF[0], bstart = BOFF[0], lvl = 0;
#pragma unroll
    for (int i = 1; i < 16; ++i)
        if (b >= BOFF[i]) { lvl = i; r = RES[i]; base = OFF[i]; bstart = BOFF[i]; }
    const int t3 = r * r * r;
    const int vstart = (b - bstart) * VPB;

    {
        const float4* ws = reinterpret_cast<const float4*>(wgt + lvl * 27 * 256);
        float4* wd = reinterpret_cast<float4*>(w_lds);
        for (int i = threadIdx.x; i < 27 * 64; i += TPB) wd[i] = ws[i];
    }
    __syncthreads();

    float bv[16];
    {
        const float4* bp = reinterpret_cast<const float4*>(bias + lvl * 16);
#pragma unroll
        for (int j = 0; j < 4; ++j) {
            float4 t = bp[j];
            bv[4*j+0] = t.x; bv[4*j+1] = t.y; bv[4*j+2] = t.z; bv[4*j+3] = t.w;
        }
    }

    int vx[VPT], vy[VPT], vz[VPT];
    bool live[VPT];
    float acc[VPT][16];
#pragma unroll
    for (int i = 0; i < VPT; ++i) {
        int v = vstart + (int)threadIdx.x + i * TPB;
        live[i] = (v < t3);
        if (!live[i]) v = 0;
        const int q = v / r;
        vz[i] = v - q * r; vx[i] = q / r; vy[i] = q - vx[i] * r;
#pragma unroll
        for (int co = 0; co < 16; ++co) acc[i][co] = bv[co];
    }

#pragma unroll 1
    for (int k = 0; k < 27; ++k) {
        const int dx = k / 9 - 1, dy = (k / 3) % 3 - 1, dz = k - (k / 3) * 3 - 1;
        float g[VPT][16];
#pragma unroll
        for (int i = 0; i < VPT; ++i) {
            const int nx = vx[i] + dx, ny = vy[i] + dy, nz = vz[i] + dz;
            const bool ok = live[i] && ((unsigned)nx < (unsigned)r) &&
                            ((unsigned)ny < (unsigned)r) && ((unsigned)nz < (unsigned)r);
            float4 a0 = make_float4(0.f,0.f,0.f,0.f), a1 = a0, a2 = a0, a3 = a0;
            if (ok) {
                const float4* p = reinterpret_cast<const float4*>(
                    in + (size_t)(base + (nx * r + ny) * r + nz) * 16);
                a0 = p[0]; a1 = p[1]; a2 = p[2]; a3 = p[3];
            }
            g[i][0]=a0.x; g[i][1]=a0.y; g[i][2]=a0.z; g[i][3]=a0.w;
            g[i][4]=a1.x; g[i][5]=a1.y; g[i][6]=a1.z; g[i][7]=a1.w;
            g[i][8]=a2.x; g[i][9]=a2.y; g[i][10]=a2.z; g[i][11]=a2.w;
            g[i][12]=a3.x; g[i][13]=a3.y; g[i][14]=a3.z; g[i][15]=a3.w;
        }
        const float4* wk = reinterpret_cast<const float4*>(&w_lds[k * 256]);
#pragma unroll
        for (int ci = 0; ci < 16; ++ci) {
            const float4 w0 = wk[ci*4+0], w1 = wk[ci*4+1], w2 = wk[ci*4+2], w3 = wk[ci*4+3];
#pragma unroll
            for (int i = 0; i < VPT; ++i) {
                const float gv = g[i][ci];
                acc[i][0]=fmaf(gv,w0.x,acc[i][0]);   acc[i][1]=fmaf(gv,w0.y,acc[i][1]);
                acc[i][2]=fmaf(gv,w0.z,acc[i][2]);   acc[i][3]=fmaf(gv,w0.w,acc[i][3]);
                acc[i][4]=fmaf(gv,w1.x,acc[i][4]);   acc[i][5]=fmaf(gv,w1.y,acc[i][5]);
                acc[i][6]=fmaf(gv,w1.z,acc[i][6]);   acc[i][7]=fmaf(gv,w1.w,acc[i][7]);
                acc[i][8]=fmaf(gv,w2.x,acc[i][8]);   acc[i][9]=fmaf(gv,w2.y,acc[i][9]);
                acc[i][10]=fmaf(gv,w2.z,acc[i][10]); acc[i][11]=fmaf(gv,w2.w,acc[i][11]);
                acc[i][12]=fmaf(gv,w3.x,acc[i][12]); acc[i][13]=fmaf(gv,w3.y,acc[i][13]);
                acc[i][14]=fmaf(gv,w3.z,acc[i][14]); acc[i][15]=fmaf(gv,w3.w,acc[i][15]);
            }
        }
    }

#pragma unroll
    for (int i = 0; i < VPT; ++i) {
        if (!live[i]) continue;
        const int v = vstart + (int)threadIdx.x + i * TPB;
        float4* po = reinterpret_cast<float4*>(out + (size_t)(base + v) * 16);
        po[0] = make_float4(acc[i][0],  acc[i][1],  acc[i][2],  acc[i][3]);
        po[1] = make_float4(acc[i][4],  acc[i][5],  acc[i][6],  acc[i][7]);
        po[2] = make_float4(acc[i][8],  acc[i][9],  acc[i][10], acc[i][11]);
        po[3] = make_float4(acc[i][12], acc[i][13], acc[i][14], acc[i][15]);
    }
}

extern "C" void kernel_launch(void* const* d_in, const int* in_sizes, int n_in,
                              void* d_out, int out_size, void* d_ws, size_t ws_size,
                              hipStream_t stream) {
    const float* in   = (const float*)d_in[0];
    const float* wgt  = (const float*)d_in[3];
    const float* bias = (const float*)d_in[4];
    float* out = (float*)d_out;

    constexpr size_t WF_BYTES = 16 * 14 * 64 * 16;   // 229,376
    if (ws_size < WF_BYTES) {
        conv3d_mr_kernel<<<NBLOCKS_F32, TPB, 0, stream>>>(in, wgt, bias, out);
        return;
    }

    uint4* wfrag = (uint4*)d_ws;
    wfrag_kernel<<<16 * 14, 64, 0, stream>>>(wgt, wfrag);
    conv_mfma_tile_kernel<<<NTILEBLKS, CTPB, 0, stream>>>(
        in, (const ushort*)wfrag, bias, out);
}

// Round 4
// 92.768 us; speedup vs baseline: 4.5833x; 1.0410x over previous
//
#include <hip/hip_runtime.h>
#include <hip/hip_bf16.h>

// Multi-resolution dense 3x3x3 conv, CIN=COUT=16, bf16 MFMA, 3D LDS tiling.
// Block = 512 thr (8 waves) owns an 8x8x16 tile. Halo 10x10x18 staged as bf16
// in LDS (two ci-half planes, 16B/voxel). Kernel offsets grouped into 5 "duos"
// by (dx,dz) with dy free: one 64-lane ds_read_b128 at halo row y' feeds the
// MFMAs of all three dy values -> 50 LDS reads / 120 MFMAs per wave (was 112/112).

typedef short bf16x8 __attribute__((ext_vector_type(8)));
typedef float f32x4  __attribute__((ext_vector_type(4)));

__device__ __forceinline__ unsigned f2bf(float f) {
    unsigned u = __float_as_uint(f);
    return (u + 0x7FFFu + ((u >> 16) & 1u)) >> 16;   // RNE
}
__device__ __forceinline__ unsigned pk2(float lo, float hi) {
    __hip_bfloat162 t = __float22bfloat162_rn(float2{lo, hi});
    return *reinterpret_cast<unsigned*>(&t);
}

// Duo tables: duo d pairs offsets (DX0[d],dy,DZ0[d]) [ksel=0] and
// (DX1[d],dy,DZ1[d]) [ksel=1]; duo4 ksel=1 is a duplicate with ZERO weights.
__device__ __constant__ int c_DX0[5] = {-1,-1, 0, 1, 1};
__device__ __constant__ int c_DZ0[5] = {-1, 1, 0,-1, 1};
__device__ __constant__ int c_DX1[5] = {-1, 0, 0, 1, 1};
__device__ __constant__ int c_DZ1[5] = { 0,-1, 1, 0, 1};

// ---------------- pass 1: weight B-fragments in duo order ----------------
// wf2[lvl][duo][dyi][lane]: 8 bf16, elem j -> w[lvl][s][ci][co],
// s = (dx+1)*9 + dyi*3 + (dz+1) with (dx,dz) = duo member (lane>>5),
// ci = ((lane>>4)&1)*8 + j, co = lane&15. duo4/ksel1 -> 0.
__global__ __launch_bounds__(64) void wfrag2_kernel(const float* __restrict__ wgt,
                                                    uint4* __restrict__ wf2) {
    const int b = blockIdx.x;                  // lvl*15 + duo*3 + dyi
    const int lvl = b / 15, rem = b % 15, duo = rem / 3, dyi = rem % 3;
    const int l = threadIdx.x;
    const int ksel = l >> 5;
    const int cib = ((l >> 4) & 1) * 8;
    const int co = l & 15;
    const bool zerow = (duo == 4) && (ksel == 1);
    const int dx = ksel ? c_DX1[duo] : c_DX0[duo];
    const int dz = ksel ? c_DZ1[duo] : c_DZ0[duo];
    const int s = (dx + 1) * 9 + dyi * 3 + (dz + 1);
    unsigned v[8];
#pragma unroll
    for (int j = 0; j < 8; ++j) {
        float f = zerow ? 0.f : wgt[(((lvl * 27 + s) * 16) + (cib + j)) * 16 + co];
        v[j] = f2bf(f);
    }
    uint4 pk;
    pk.x = v[0] | (v[1] << 16);
    pk.y = v[2] | (v[3] << 16);
    pk.z = v[4] | (v[5] << 16);
    pk.w = v[6] | (v[7] << 16);
    wf2[((lvl * 5 + duo) * 3 + dyi) * 64 + l] = pk;
}

// ---------------- pass 2: tiled MFMA conv ----------------
#define CTPB 512
#define NTILEBLKS 2465
#define PLANE 28800          // 1800 halo voxels * 16B per ci-half plane

__global__ __launch_bounds__(CTPB, 4) void conv_mfma_tile_kernel(
    const float* __restrict__ in, const ushort* __restrict__ wf2,
    const float* __restrict__ bias, float* __restrict__ out)
{
    constexpr int RES[16]   = {16, 18, 20, 23, 26, 29, 32, 36, 40, 45, 50, 56, 63, 70, 76, 80};
    constexpr int OFF[16]   = {0, 4096, 9928, 17928, 30095, 47671, 72060, 104828,
                               151484, 215484, 306609, 431609, 607225, 857272, 1200272, 1639248};
    constexpr int TBOFF[16] = {0, 4, 22, 40, 58, 90, 122, 154, 229, 304, 412, 608, 804, 1060, 1465, 1965};
    // per-duo LDS byte shifts: (dx*180 + dz)*16 for members 0/1
    constexpr int SH0[5] = {-2896, -2864, 0, 2864, 2896};
    constexpr int SH1[5] = {-2880, -16, 16, 2880, 2896};

    __shared__ __align__(16) char lds[2 * PLANE];   // 57.6 KB

    const int b = blockIdx.x;
    int lvl = 0;
#pragma unroll
    for (int i = 1; i < 16; ++i) if (b >= TBOFF[i]) lvl = i;
    const int r    = RES[lvl];
    const int base = OFF[lvl];

    const int NTZ = (r + 15) >> 4;
    const int NTY = (r + 7) >> 3;
    int tid = b - TBOFF[lvl];
    const int nyz = NTY * NTZ;
    const int txi = tid / nyz;  tid -= txi * nyz;
    const int tyi = tid / NTZ;
    const int tzi = tid - tyi * NTZ;
    const int x0 = txi * 8, y0 = tyi * 8, z0 = tzi * 16;

    const int lane = threadIdx.x & 63;
    const int wave = threadIdx.x >> 6;

    // ---- stage halo: fp32 global -> bf16 LDS (zeros outside level bounds) ----
    // plane-block-major: consecutive lanes write consecutive 16B (conflict-free).
    for (int j = threadIdx.x; j < 3600; j += CTPB) {
        const int half = (j >= 1800) ? 1 : 0;
        const int h = j - half * 1800;
        const int hx = h / 180;
        const int rem = h - hx * 180;
        const int hy = rem / 18;
        const int hz = rem - hy * 18;
        const int gx = x0 - 1 + hx, gy = y0 - 1 + hy, gz = z0 - 1 + hz;
        uint4 pk = {0u, 0u, 0u, 0u};
        if (((unsigned)gx < (unsigned)r) & ((unsigned)gy < (unsigned)r) &
            ((unsigned)gz < (unsigned)r)) {
            const float4* s = reinterpret_cast<const float4*>(
                in + ((size_t)base + ((size_t)gx * r + gy) * r + gz) * 16 + half * 8);
            const float4 a = s[0], c2 = s[1];
            pk.x = pk2(a.x,  a.y);
            pk.y = pk2(a.z,  a.w);
            pk.z = pk2(c2.x, c2.y);
            pk.w = pk2(c2.z, c2.w);
        }
        *reinterpret_cast<uint4*>(lds + half * PLANE + h * 16) = pk;
    }
    __syncthreads();

    // ---- compute: wave = x slice tx, 8 y-columns, 5 duos x (10 reads + 24 MFMA) ----
    const int m      = lane & 15;         // MFMA A row = z within tile
    const int cihalf = (lane >> 4) & 1;
    const int ksel   = lane >> 5;
    const int tx     = wave;

    // lane base at duo-shift 0, halo row y'=0: voxel (tx+1, 0, 1+m), half=cihalf
    const int base0 = cihalf * PLANE + (((tx + 1) * 180) + 1 + m) * 16;

    f32x4 acc[8];
#pragma unroll
    for (int i = 0; i < 8; ++i) acc[i] = f32x4{0.f, 0.f, 0.f, 0.f};

#pragma unroll
    for (int d = 0; d < 5; ++d) {
        const int shift = ksel ? SH1[d] : SH0[d];
        const char* gp = lds + (base0 + shift);

        const bf16x8* wl = (const bf16x8*)wf2 + ((size_t)(lvl * 5 + d) * 3) * 64 + lane;
        const bf16x8 W0 = wl[0];          // dy = -1
        const bf16x8 W1 = wl[64];         // dy =  0
        const bf16x8 W2 = wl[128];        // dy = +1

        bf16x8 G[10];
#pragma unroll
        for (int y = 0; y < 10; ++y)
            G[y] = *reinterpret_cast<const bf16x8*>(gp + y * 288);

#pragma unroll
        for (int i = 0; i < 8; ++i)
            acc[i] = __builtin_amdgcn_mfma_f32_16x16x32_bf16(G[i],     W0, acc[i], 0, 0, 0);
#pragma unroll
        for (int i = 0; i < 8; ++i)
            acc[i] = __builtin_amdgcn_mfma_f32_16x16x32_bf16(G[i + 1], W1, acc[i], 0, 0, 0);
#pragma unroll
        for (int i = 0; i < 8; ++i)
            acc[i] = __builtin_amdgcn_mfma_f32_16x16x32_bf16(G[i + 2], W2, acc[i], 0, 0, 0);
    }

    // ---- store (+bias); C layout: col=lane&15=co, row=(lane>>4)*4+reg ----
    const int co = m;
    const float bv = bias[lvl * 16 + co];
    const int gx = x0 + tx;
    if (gx < r) {
#pragma unroll
        for (int i = 0; i < 8; ++i) {
            const int gy = y0 + i;
            if (gy >= r) continue;
            const size_t vb = (size_t)base + ((size_t)gx * r + gy) * r + z0;
#pragma unroll
            for (int j2 = 0; j2 < 4; ++j2) {
                const int row = (lane >> 4) * 4 + j2;
                if (z0 + row < r) out[(vb + row) * 16 + co] = acc[i][j2] + bv;
            }
        }
    }
}

// ---------------- fp32 fallback (round-0 verified, used only if ws tiny) -----
#define TPB 256
#define VPT 2
#define VPB (TPB * VPT)
#define NBLOCKS_F32 4207

__global__ __launch_bounds__(TPB) void conv3d_mr_kernel(
    const float* __restrict__ in, const float* __restrict__ wgt,
    const float* __restrict__ bias, float* __restrict__ out)
{
    constexpr int RES[16]  = {16, 18, 20, 23, 26, 29, 32, 36, 40, 45, 50, 56, 63, 70, 76, 80};
    constexpr int OFF[16]  = {0, 4096, 9928, 17928, 30095, 47671, 72060, 104828,
                              151484, 215484, 306609, 431609, 607225, 857272, 1200272, 1639248};
    constexpr int BOFF[16] = {0, 8, 20, 36, 60, 95, 143, 207, 299, 424, 602, 847, 1190, 1679, 2349, 3207};

    __shared__ __align__(16) float w_lds[27 * 256];

    const int b = blockIdx.x;
    int r = RES[0], base = OFF[0], bstart = BOFF[0], lvl = 0;
#pragma unroll
    for (int i = 1; i < 16; ++i)
        if (b >= BOFF[i]) { lvl = i; r = RES[i]; base = OFF[i]; bstart = BOFF[i]; }
    const int t3 = r * r * r;
    const int vstart = (b - bstart) * VPB;

    {
        const float4* ws = reinterpret_cast<const float4*>(wgt + lvl * 27 * 256);
        float4* wd = reinterpret_cast<float4*>(w_lds);
        for (int i = threadIdx.x; i < 27 * 64; i += TPB) wd[i] = ws[i];
    }
    __syncthreads();

    float bv[16];
    {
        const float4* bp = reinterpret_cast<const float4*>(bias + lvl * 16);
#pragma unroll
        for (int j = 0; j < 4; ++j) {
            float4 t = bp[j];
            bv[4*j+0] = t.x; bv[4*j+1] = t.y; bv[4*j+2] = t.z; bv[4*j+3] = t.w;
        }
    }

    int vx[VPT], vy[VPT], vz[VPT];
    bool live[VPT];
    float acc[VPT][16];
#pragma unroll
    for (int i = 0; i < VPT; ++i) {
        int v = vstart + (int)threadIdx.x + i * TPB;
        live[i] = (v < t3);
        if (!live[i]) v = 0;
        const int q = v / r;
        vz[i] = v - q * r; vx[i] = q / r; vy[i] = q - vx[i] * r;
#pragma unroll
        for (int co = 0; co < 16; ++co) acc[i][co] = bv[co];
    }

#pragma unroll 1
    for (int k = 0; k < 27; ++k) {
        const int dx = k / 9 - 1, dy = (k / 3) % 3 - 1, dz = k - (k / 3) * 3 - 1;
        float g[VPT][16];
#pragma unroll
        for (int i = 0; i < VPT; ++i) {
            const int nx = vx[i] + dx, ny = vy[i] + dy, nz = vz[i] + dz;
            const bool ok = live[i] && ((unsigned)nx < (unsigned)r) &&
                            ((unsigned)ny < (unsigned)r) && ((unsigned)nz < (unsigned)r);
            float4 a0 = make_float4(0.f,0.f,0.f,0.f), a1 = a0, a2 = a0, a3 = a0;
            if (ok) {
                const float4* p = reinterpret_cast<const float4*>(
                    in + (size_t)(base + (nx * r + ny) * r + nz) * 16);
                a0 = p[0]; a1 = p[1]; a2 = p[2]; a3 = p[3];
            }
            g[i][0]=a0.x; g[i][1]=a0.y; g[i][2]=a0.z; g[i][3]=a0.w;
            g[i][4]=a1.x; g[i][5]=a1.y; g[i][6]=a1.z; g[i][7]=a1.w;
            g[i][8]=a2.x; g[i][9]=a2.y; g[i][10]=a2.z; g[i][11]=a2.w;
            g[i][12]=a3.x; g[i][13]=a3.y; g[i][14]=a3.z; g[i][15]=a3.w;
        }
        const float4* wk = reinterpret_cast<const float4*>(&w_lds[k * 256]);
#pragma unroll
        for (int ci = 0; ci < 16; ++ci) {
            const float4 w0 = wk[ci*4+0], w1 = wk[ci*4+1], w2 = wk[ci*4+2], w3 = wk[ci*4+3];
#pragma unroll
            for (int i = 0; i < VPT; ++i) {
                const float gv = g[i][ci];
                acc[i][0]=fmaf(gv,w0.x,acc[i][0]);   acc[i][1]=fmaf(gv,w0.y,acc[i][1]);
                acc[i][2]=fmaf(gv,w0.z,acc[i][2]);   acc[i][3]=fmaf(gv,w0.w,acc[i][3]);
                acc[i][4]=fmaf(gv,w1.x,acc[i][4]);   acc[i][5]=fmaf(gv,w1.y,acc[i][5]);
                acc[i][6]=fmaf(gv,w1.z,acc[i][6]);   acc[i][7]=fmaf(gv,w1.w,acc[i][7]);
                acc[i][8]=fmaf(gv,w2.x,acc[i][8]);   acc[i][9]=fmaf(gv,w2.y,acc[i][9]);
                acc[i][10]=fmaf(gv,w2.z,acc[i][10]); acc[i][11]=fmaf(gv,w2.w,acc[i][11]);
                acc[i][12]=fmaf(gv,w3.x,acc[i][12]); acc[i][13]=fmaf(gv,w3.y,acc[i][13]);
                acc[i][14]=fmaf(gv,w3.z,acc[i][14]); acc[i][15]=fmaf(gv,w3.w,acc[i][15]);
            }
        }
    }

#pragma unroll
    for (int i = 0; i < VPT; ++i) {
        if (!live[i]) continue;
        const int v = vstart + (int)threadIdx.x + i * TPB;
        float4* po = reinterpret_cast<float4*>(out + (size_t)(base + v) * 16);
        po[0] = make_float4(acc[i][0],  acc[i][1],  acc[i][2],  acc[i][3]);
        po[1] = make_float4(acc[i][4],  acc[i][5],  acc[i][6],  acc[i][7]);
        po[2] = make_float4(acc[i][8],  acc[i][9],  acc[i][10], acc[i][11]);
        po[3] = make_float4(acc[i][12], acc[i][13], acc[i][14], acc[i][15]);
    }
}

extern "C" void kernel_launch(void* const* d_in, const int* in_sizes, int n_in,
                              void* d_out, int out_size, void* d_ws, size_t ws_size,
                              hipStream_t stream) {
    const float* in   = (const float*)d_in[0];
    const float* wgt  = (const float*)d_in[3];
    const float* bias = (const float*)d_in[4];
    float* out = (float*)d_out;

    constexpr size_t WF2_BYTES = 16 * 5 * 3 * 64 * 16;   // 245,760
    if (ws_size < WF2_BYTES) {
        conv3d_mr_kernel<<<NBLOCKS_F32, TPB, 0, stream>>>(in, wgt, bias, out);
        return;
    }

    uint4* wf2 = (uint4*)d_ws;
    wfrag2_kernel<<<16 * 5 * 3, 64, 0, stream>>>(wgt, wf2);
    conv_mfma_tile_kernel<<<NTILEBLKS, CTPB, 0, stream>>>(
        in, (const ushort*)wf2, bias, out);
}

// Round 5
// 84.460 us; speedup vs baseline: 5.0341x; 1.0984x over previous
//
#include <hip/hip_runtime.h>
#include <hip/hip_bf16.h>

// Multi-resolution dense 3x3x3 conv, CIN=COUT=16, bf16 MFMA, 3D LDS tiling.
// R4: tile shrunk to 4x4x16 (halo 6x6x18 = 20.7 KB LDS) so 7 blocks/CU fit
// (28 waves/CU cap, was 2 blocks/16 waves) -> stage/compute phases of many
// independent blocks overlap. Wave = x-slice; 5 (dx,dz)-duos x 3 dy, one
// ds_read_b128 row feeds 3 MFMAs (y-reuse). Bijective XCD swizzle keeps
// neighboring tiles on one XCD's L2 to absorb halo re-reads.

typedef short bf16x8 __attribute__((ext_vector_type(8)));
typedef float f32x4  __attribute__((ext_vector_type(4)));

__device__ __forceinline__ unsigned f2bf(float f) {
    unsigned u = __float_as_uint(f);
    return (u + 0x7FFFu + ((u >> 16) & 1u)) >> 16;   // RNE
}
__device__ __forceinline__ unsigned pk2(float lo, float hi) {
    __hip_bfloat162 t = __float22bfloat162_rn(float2{lo, hi});
    return *reinterpret_cast<unsigned*>(&t);
}

// Duo tables: duo d pairs offsets (DX0[d],dy,DZ0[d]) [ksel=0] and
// (DX1[d],dy,DZ1[d]) [ksel=1]; duo4 ksel=1 is a duplicate with ZERO weights.
__device__ __constant__ int c_DX0[5] = {-1,-1, 0, 1, 1};
__device__ __constant__ int c_DZ0[5] = {-1, 1, 0,-1, 1};
__device__ __constant__ int c_DX1[5] = {-1, 0, 0, 1, 1};
__device__ __constant__ int c_DZ1[5] = { 0,-1, 1, 0, 1};

// ---------------- pass 1: weight B-fragments in duo order ----------------
// wf2[lvl][duo][dyi][lane]: 8 bf16, elem j -> w[lvl][s][ci][co],
// s = (dx+1)*9 + dyi*3 + (dz+1) with (dx,dz) = duo member (lane>>5),
// ci = ((lane>>4)&1)*8 + j, co = lane&15. duo4/ksel1 -> 0.
__global__ __launch_bounds__(64) void wfrag2_kernel(const float* __restrict__ wgt,
                                                    uint4* __restrict__ wf2) {
    const int b = blockIdx.x;                  // lvl*15 + duo*3 + dyi
    const int lvl = b / 15, rem = b % 15, duo = rem / 3, dyi = rem % 3;
    const int l = threadIdx.x;
    const int ksel = l >> 5;
    const int cib = ((l >> 4) & 1) * 8;
    const int co = l & 15;
    const bool zerow = (duo == 4) && (ksel == 1);
    const int dx = ksel ? c_DX1[duo] : c_DX0[duo];
    const int dz = ksel ? c_DZ1[duo] : c_DZ0[duo];
    const int s = (dx + 1) * 9 + dyi * 3 + (dz + 1);
    unsigned v[8];
#pragma unroll
    for (int j = 0; j < 8; ++j) {
        float f = zerow ? 0.f : wgt[(((lvl * 27 + s) * 16) + (cib + j)) * 16 + co];
        v[j] = f2bf(f);
    }
    uint4 pk;
    pk.x = v[0] | (v[1] << 16);
    pk.y = v[2] | (v[3] << 16);
    pk.z = v[4] | (v[5] << 16);
    pk.w = v[6] | (v[7] << 16);
    wf2[((lvl * 5 + duo) * 3 + dyi) * 64 + l] = pk;
}

// ---------------- pass 2: tiled MFMA conv ----------------
#define CTPB 256
#define NTILEBLKS 9426
#define PLANE 10368          // 648 halo voxels * 16B per ci-half plane

__global__ __launch_bounds__(CTPB, 7) void conv_mfma_tile_kernel(
    const float* __restrict__ in, const ushort* __restrict__ wf2,
    const float* __restrict__ bias, float* __restrict__ out)
{
    constexpr int RES[16]   = {16, 18, 20, 23, 26, 29, 32, 36, 40, 45, 50, 56, 63, 70, 76, 80};
    constexpr int OFF[16]   = {0, 4096, 9928, 17928, 30095, 47671, 72060, 104828,
                               151484, 215484, 306609, 431609, 607225, 857272, 1200272, 1639248};
    // tiles per level = ceil(r/4)^2 * ceil(r/16); prefix:
    constexpr int TBOFF[16] = {0, 16, 66, 116, 188, 286, 414, 542, 785, 1085,
                               1517, 2193, 2977, 4001, 5621, 7426};
    // per-duo LDS byte shifts: (dx*108 + dz)*16 for members 0/1
    constexpr int SH0[5] = {-1744, -1712, 0, 1712, 1744};
    constexpr int SH1[5] = {-1728, -16, 16, 1728, 1744};

    __shared__ __align__(16) char lds[2 * PLANE];   // 20.7 KB

    // Bijective XCD swizzle (nwg=9426, q=1178, r=2): neighbors share an XCD L2.
    const int orig = blockIdx.x;
    const int xcd = orig & 7, idx = orig >> 3;
    const int b = (xcd < 2 ? xcd * 1179 : 2 * 1179 + (xcd - 2) * 1178) + idx;

    int lvl = 0;
#pragma unroll
    for (int i = 1; i < 16; ++i) if (b >= TBOFF[i]) lvl = i;
    const int r    = RES[lvl];
    const int base = OFF[lvl];

    const int NTZ = (r + 15) >> 4;
    const int NTY = (r + 3) >> 2;
    int tid = b - TBOFF[lvl];
    const int nyz = NTY * NTZ;
    const int txi = tid / nyz;  tid -= txi * nyz;
    const int tyi = tid / NTZ;
    const int tzi = tid - tyi * NTZ;
    const int x0 = txi * 4, y0 = tyi * 4, z0 = tzi * 16;

    const int lane = threadIdx.x & 63;
    const int wave = threadIdx.x >> 6;

    // ---- stage halo: fp32 global -> bf16 LDS (zeros outside level bounds) ----
    // half=j&1: lane pairs read consecutive 32B (fully coalesced); LDS writes
    // alternate planes -> 2-way bank aliasing (free).
    for (int j = threadIdx.x; j < 1296; j += CTPB) {
        const int half = j & 1;
        const int h = j >> 1;
        const int hx = h / 108;
        const int rem = h - hx * 108;
        const int hy = rem / 18;
        const int hz = rem - hy * 18;
        const int gx = x0 - 1 + hx, gy = y0 - 1 + hy, gz = z0 - 1 + hz;
        uint4 pk = {0u, 0u, 0u, 0u};
        if (((unsigned)gx < (unsigned)r) & ((unsigned)gy < (unsigned)r) &
            ((unsigned)gz < (unsigned)r)) {
            const float4* s = reinterpret_cast<const float4*>(
                in + ((size_t)base + ((size_t)gx * r + gy) * r + gz) * 16 + half * 8);
            const float4 a = s[0], c2 = s[1];
            pk.x = pk2(a.x,  a.y);
            pk.y = pk2(a.z,  a.w);
            pk.z = pk2(c2.x, c2.y);
            pk.w = pk2(c2.z, c2.w);
        }
        *reinterpret_cast<uint4*>(lds + half * PLANE + h * 16) = pk;
    }
    __syncthreads();

    // ---- compute: wave = x-slice tx, 4 y-cols, 5 duos x (6 reads + 12 MFMA) ----
    const int m      = lane & 15;         // MFMA A row = z within tile
    const int cihalf = (lane >> 4) & 1;
    const int ksel   = lane >> 5;
    const int tx     = wave;

    // lane base at duo-shift 0, halo row y'=0: voxel (tx+1, 0, 1+m)
    const int base0 = cihalf * PLANE + ((tx + 1) * 108 + 1 + m) * 16;

    f32x4 acc[4];
#pragma unroll
    for (int i = 0; i < 4; ++i) acc[i] = f32x4{0.f, 0.f, 0.f, 0.f};

#pragma unroll
    for (int d = 0; d < 5; ++d) {
        const int shift = ksel ? SH1[d] : SH0[d];
        const char* gp = lds + (base0 + shift);

        const bf16x8* wl = (const bf16x8*)wf2 + ((size_t)(lvl * 5 + d) * 3) * 64 + lane;
        const bf16x8 W0 = wl[0];          // dy = -1
        const bf16x8 W1 = wl[64];         // dy =  0
        const bf16x8 W2 = wl[128];        // dy = +1

        bf16x8 G[6];
#pragma unroll
        for (int y = 0; y < 6; ++y)
            G[y] = *reinterpret_cast<const bf16x8*>(gp + y * 288);

#pragma unroll
        for (int i = 0; i < 4; ++i)
            acc[i] = __builtin_amdgcn_mfma_f32_16x16x32_bf16(G[i],     W0, acc[i], 0, 0, 0);
#pragma unroll
        for (int i = 0; i < 4; ++i)
            acc[i] = __builtin_amdgcn_mfma_f32_16x16x32_bf16(G[i + 1], W1, acc[i], 0, 0, 0);
#pragma unroll
        for (int i = 0; i < 4; ++i)
            acc[i] = __builtin_amdgcn_mfma_f32_16x16x32_bf16(G[i + 2], W2, acc[i], 0, 0, 0);
    }

    // ---- store (+bias); C layout: col=lane&15=co, row=(lane>>4)*4+reg ----
    const int co = m;
    const float bv = bias[lvl * 16 + co];
    const int gx = x0 + tx;
    if (gx < r) {
#pragma unroll
        for (int i = 0; i < 4; ++i) {
            const int gy = y0 + i;
            if (gy >= r) continue;
            const size_t vb = (size_t)base + ((size_t)gx * r + gy) * r + z0;
#pragma unroll
            for (int j2 = 0; j2 < 4; ++j2) {
                const int row = (lane >> 4) * 4 + j2;
                if (z0 + row < r) out[(vb + row) * 16 + co] = acc[i][j2] + bv;
            }
        }
    }
}

// ---------------- fp32 fallback (round-0 verified, used only if ws tiny) -----
#define TPB 256
#define VPT 2
#define VPB (TPB * VPT)
#define NBLOCKS_F32 4207

__global__ __launch_bounds__(TPB) void conv3d_mr_kernel(
    const float* __restrict__ in, const float* __restrict__ wgt,
    const float* __restrict__ bias, float* __restrict__ out)
{
    constexpr int RES[16]  = {16, 18, 20, 23, 26, 29, 32, 36, 40, 45, 50, 56, 63, 70, 76, 80};
    constexpr int OFF[16]  = {0, 4096, 9928, 17928, 30095, 47671, 72060, 104828,
                              151484, 215484, 306609, 431609, 607225, 857272, 1200272, 1639248};
    constexpr int BOFF[16] = {0, 8, 20, 36, 60, 95, 143, 207, 299, 424, 602, 847, 1190, 1679, 2349, 3207};

    __shared__ __align__(16) float w_lds[27 * 256];

    const int b = blockIdx.x;
    int r = RES[0], base = OFF[0], bstart = BOFF[0], lvl = 0;
#pragma unroll
    for (int i = 1; i < 16; ++i)
        if (b >= BOFF[i]) { lvl = i; r = RES[i]; base = OFF[i]; bstart = BOFF[i]; }
    const int t3 = r * r * r;
    const int vstart = (b - bstart) * VPB;

    {
        const float4* ws = reinterpret_cast<const float4*>(wgt + lvl * 27 * 256);
        float4* wd = reinterpret_cast<float4*>(w_lds);
        for (int i = threadIdx.x; i < 27 * 64; i += TPB) wd[i] = ws[i];
    }
    __syncthreads();

    float bv[16];
    {
        const float4* bp = reinterpret_cast<const float4*>(bias + lvl * 16);
#pragma unroll
        for (int j = 0; j < 4; ++j) {
            float4 t = bp[j];
            bv[4*j+0] = t.x; bv[4*j+1] = t.y; bv[4*j+2] = t.z; bv[4*j+3] = t.w;
        }
    }

    int vx[VPT], vy[VPT], vz[VPT];
    bool live[VPT];
    float acc[VPT][16];
#pragma unroll
    for (int i = 0; i < VPT; ++i) {
        int v = vstart + (int)threadIdx.x + i * TPB;
        live[i] = (v < t3);
        if (!live[i]) v = 0;
        const int q = v / r;
        vz[i] = v - q * r; vx[i] = q / r; vy[i] = q - vx[i] * r;
#pragma unroll
        for (int co = 0; co < 16; ++co) acc[i][co] = bv[co];
    }

#pragma unroll 1
    for (int k = 0; k < 27; ++k) {
        const int dx = k / 9 - 1, dy = (k / 3) % 3 - 1, dz = k - (k / 3) * 3 - 1;
        float g[VPT][16];
#pragma unroll
        for (int i = 0; i < VPT; ++i) {
            const int nx = vx[i] + dx, ny = vy[i] + dy, nz = vz[i] + dz;
            const bool ok = live[i] && ((unsigned)nx < (unsigned)r) &&
                            ((unsigned)ny < (unsigned)r) && ((unsigned)nz < (unsigned)r);
            float4 a0 = make_float4(0.f,0.f,0.f,0.f), a1 = a0, a2 = a0, a3 = a0;
            if (ok) {
                const float4* p = reinterpret_cast<const float4*>(
                    in + (size_t)(base + (nx * r + ny) * r + nz) * 16);
                a0 = p[0]; a1 = p[1]; a2 = p[2]; a3 = p[3];
            }
            g[i][0]=a0.x; g[i][1]=a0.y; g[i][2]=a0.z; g[i][3]=a0.w;
            g[i][4]=a1.x; g[i][5]=a1.y; g[i][6]=a1.z; g[i][7]=a1.w;
            g[i][8]=a2.x; g[i][9]=a2.y; g[i][10]=a2.z; g[i][11]=a2.w;
            g[i][12]=a3.x; g[i][13]=a3.y; g[i][14]=a3.z; g[i][15]=a3.w;
        }
        const float4* wk = reinterpret_cast<const float4*>(&w_lds[k * 256]);
#pragma unroll
        for (int ci = 0; ci < 16; ++ci) {
            const float4 w0 = wk[ci*4+0], w1 = wk[ci*4+1], w2 = wk[ci*4+2], w3 = wk[ci*4+3];
#pragma unroll
            for (int i = 0; i < VPT; ++i) {
                const float gv = g[i][ci];
                acc[i][0]=fmaf(gv,w0.x,acc[i][0]);   acc[i][1]=fmaf(gv,w0.y,acc[i][1]);
                acc[i][2]=fmaf(gv,w0.z,acc[i][2]);   acc[i][3]=fmaf(gv,w0.w,acc[i][3]);
                acc[i][4]=fmaf(gv,w1.x,acc[i][4]);   acc[i][5]=fmaf(gv,w1.y,acc[i][5]);
                acc[i][6]=fmaf(gv,w1.z,acc[i][6]);   acc[i][7]=fmaf(gv,w1.w,acc[i][7]);
                acc[i][8]=fmaf(gv,w2.x,acc[i][8]);   acc[i][9]=fmaf(gv,w2.y,acc[i][9]);
                acc[i][10]=fmaf(gv,w2.z,acc[i][10]); acc[i][11]=fmaf(gv,w2.w,acc[i][11]);
                acc[i][12]=fmaf(gv,w3.x,acc[i][12]); acc[i][13]=fmaf(gv,w3.y,acc[i][13]);
                acc[i][14]=fmaf(gv,w3.z,acc[i][14]); acc[i][15]=fmaf(gv,w3.w,acc[i][15]);
            }
        }
    }

#pragma unroll
    for (int i = 0; i < VPT; ++i) {
        if (!live[i]) continue;
        const int v = vstart + (int)threadIdx.x + i * TPB;
        float4* po = reinterpret_cast<float4*>(out + (size_t)(base + v) * 16);
        po[0] = make_float4(acc[i][0],  acc[i][1],  acc[i][2],  acc[i][3]);
        po[1] = make_float4(acc[i][4],  acc[i][5],  acc[i][6],  acc[i][7]);
        po[2] = make_float4(acc[i][8],  acc[i][9],  acc[i][10], acc[i][11]);
        po[3] = make_float4(acc[i][12], acc[i][13], acc[i][14], acc[i][15]);
    }
}

extern "C" void kernel_launch(void* const* d_in, const int* in_sizes, int n_in,
                              void* d_out, int out_size, void* d_ws, size_t ws_size,
                              hipStream_t stream) {
    const float* in   = (const float*)d_in[0];
    const float* wgt  = (const float*)d_in[3];
    const float* bias = (const float*)d_in[4];
    float* out = (float*)d_out;

    constexpr size_t WF2_BYTES = 16 * 5 * 3 * 64 * 16;   // 245,760
    if (ws_size < WF2_BYTES) {
        conv3d_mr_kernel<<<NBLOCKS_F32, TPB, 0, stream>>>(in, wgt, bias, out);
        return;
    }

    uint4* wf2 = (uint4*)d_ws;
    wfrag2_kernel<<<16 * 5 * 3, 64, 0, stream>>>(wgt, wf2);
    conv_mfma_tile_kernel<<<NTILEBLKS, CTPB, 0, stream>>>(
        in, (const ushort*)wf2, bias, out);
}